// Round 1
// 3248.957 us; speedup vs baseline: 1.0103x; 1.0103x over previous
//
#include <hip/hip_runtime.h>
#include <hip/hip_bf16.h>
#include <stdint.h>

// Problem constants
#define B   32
#define TX  128
#define TY  64
#define VCB 50000
#define D   128
#define H   256
#define G4  1024   // 4*H
#define TT  192    // TX+TY

typedef unsigned short ushort_t;

__device__ __forceinline__ float b2f(ushort_t u) {
    union { unsigned int i; float f; } v;
    v.i = ((unsigned int)u) << 16;
    return v.f;
}

__device__ __forceinline__ ushort_t f2b(float f) {
    union { float f; unsigned int i; } v;
    v.f = f;
    unsigned int i = v.i;
    unsigned int r = (i + 0x7fffu + ((i >> 16) & 1u)) >> 16;  // RNE
    return (ushort_t)r;
}

// Flag-aware load: isf32 ? fp32 array : bf16 array. Branch is wave-uniform.
__device__ __forceinline__ float ldf(const void* p, size_t i, int isf32) {
    if (isf32) return ((const float*)p)[i];
    return b2f(((const ushort_t*)p)[i]);
}

// ---------------------------------------------------------------------------
// Kernel 0: dtype detection. Interpret E's first 4096 u16 as bf16; genuine
// bf16 data (normal*0.05) has max|v| ~0.25. fp32 data's low-half u16s have
// random exponent bits -> max|v| is astronomically large. flag=1 => fp32.
// ---------------------------------------------------------------------------
__global__ __launch_bounds__(256) void detect_dtype(const ushort_t* __restrict__ E16,
                                                    int* __restrict__ flag) {
    __shared__ float red[256];
    int tid = threadIdx.x;
    float m = 0.f;
#pragma unroll
    for (int j = 0; j < 16; ++j) {
        float v = fabsf(b2f(E16[tid * 16 + j]));
        if (v > m) m = v;
    }
    red[tid] = m;
    __syncthreads();
    for (int s = 128; s > 0; s >>= 1) {
        if (tid < s && red[tid + s] > red[tid]) red[tid] = red[tid + s];
        __syncthreads();
    }
    if (tid == 0) flag[0] = (red[0] > 1.0f) ? 1 : 0;
}

// ---------------------------------------------------------------------------
// Kernel 0b: canonicalize LSTM weights/biases to fp32 (exact either way).
// ---------------------------------------------------------------------------
__global__ __launch_bounds__(256) void canon_w(const void* __restrict__ We,
                                               const void* __restrict__ be,
                                               const void* __restrict__ Wd,
                                               const void* __restrict__ bd,
                                               float* __restrict__ Wce,
                                               float* __restrict__ bce,
                                               float* __restrict__ Wcd,
                                               float* __restrict__ bcd,
                                               const int* __restrict__ flag) {
    int isf32 = *flag;
    int i = blockIdx.x * 256 + threadIdx.x;
    const int NW = (D + H) * G4;   // 393216
    if (i < NW) {
        Wce[i] = ldf(We, i, isf32);
        Wcd[i] = ldf(Wd, i, isf32);
    }
    if (i < G4) {
        bce[i] = ldf(be, i, isf32);
        bcd[i] = ldf(bd, i, isf32);
    }
}

// ---------------------------------------------------------------------------
// Kernel 0c: pack recurrent weights Wh (rows [D, D+H) of Wc) into a
// per-thread-contiguous layout for the fused LSTM kernel:
//   Wpk[((kb*512 + p)*8 + u)*2 + j] = Wc[(D + kb*8 + u)*G4 + 2*p + j]
// so thread p's 8 k-values for its two columns (2p, 2p+1) are 64B contiguous
// -> 4x global_load_dwordx4 from one base with imm offsets per k-block.
// ---------------------------------------------------------------------------
__global__ __launch_bounds__(256) void pack_wh(const float* __restrict__ Wce,
                                               const float* __restrict__ Wcd,
                                               float* __restrict__ WpkE,
                                               float* __restrict__ WpkD) {
    size_t i = (size_t)blockIdx.x * 256 + threadIdx.x;  // 0 .. 262143
    int j  = (int)(i & 1);
    int u  = (int)((i >> 1) & 7);
    int p  = (int)((i >> 4) & 511);
    int kb = (int)(i >> 13);
    size_t src = (size_t)(D + kb * 8 + u) * G4 + 2 * p + j;
    if (blockIdx.y == 0) WpkE[i] = Wce[src];
    else                 WpkD[i] = Wcd[src];
}

// ---------------------------------------------------------------------------
// Kernel 1: transpose W_proj (H x V) -> WpT (V x H) bf16, k-contiguous rows.
// ---------------------------------------------------------------------------
__global__ __launch_bounds__(256) void transpose_wp(const void* __restrict__ Wp,
                                                    ushort_t* __restrict__ WpT,
                                                    const int* __restrict__ flag) {
    int isf32 = *flag;
    int v0 = blockIdx.x * 64;
    int k0 = blockIdx.y * 64;
    __shared__ ushort_t tile[64][65];
    int tid = threadIdx.x;
    int vl = tid & 63, p0 = tid >> 6;     // p0 in [0,4)
    for (int p = 0; p < 16; ++p) {
        int k = k0 + p0 + p * 4;          // k < 256 always
        int v = v0 + vl;
        float x = (v < VCB) ? ldf(Wp, (size_t)k * VCB + v, isf32) : 0.f;
        tile[p0 + p * 4][vl] = f2b(x);
    }
    __syncthreads();
    int kl = tid & 63, q0 = tid >> 6;
    for (int p = 0; p < 16; ++p) {
        int v = v0 + q0 + p * 4;
        if (v < VCB) WpT[(size_t)v * H + (k0 + kl)] = tile[kl][q0 + p * 4];
    }
}

// ---------------------------------------------------------------------------
// Kernel 2: embedding gather + x-part of gate GEMM for all 192 steps (fp32).
// xz[t][b][g] = sum_k emb(t,b,k) * Wx[k][g] + bias[g]
// ---------------------------------------------------------------------------
__global__ __launch_bounds__(128) void embed_xw(const int* __restrict__ enc_in,
                                                const int* __restrict__ dec_in,
                                                const void* __restrict__ E,
                                                const float* __restrict__ Wce,
                                                const float* __restrict__ bce,
                                                const float* __restrict__ Wcd,
                                                const float* __restrict__ bcd,
                                                float* __restrict__ xz,
                                                const int* __restrict__ flag) {
    int isf32 = *flag;
    int t  = blockIdx.y;          // 0..191
    int n0 = blockIdx.x * 64;     // 16 n-slices
    int tid = threadIdx.x;        // 0..127 (= k index)
    __shared__ float embT[D][33]; // [k][b], padded
    __shared__ int tok[B];

    const float* Wc   = (t < TX) ? Wce : Wcd;
    const float* bias = (t < TX) ? bce : bcd;

    if (tid < B)
        tok[tid] = (t < TX) ? enc_in[tid * TX + t] : dec_in[tid * TY + (t - TX)];
    __syncthreads();

    for (int p = 0; p < B; ++p)
        embT[tid][p] = ldf(E, (size_t)tok[p] * D + tid, isf32);
    __syncthreads();

    int nl = tid & 31;            // n-pair index
    int bg = tid >> 5;            // 0..3
    int n  = n0 + nl * 2;
    int b0 = bg * 8;
    float acc[8][2];
    float bi0 = bias[n], bi1 = bias[n + 1];
#pragma unroll
    for (int r = 0; r < 8; ++r) { acc[r][0] = bi0; acc[r][1] = bi1; }

    for (int k = 0; k < D; ++k) {
        const float* wr = Wc + (size_t)k * G4 + n;
        float w0 = wr[0], w1 = wr[1];
#pragma unroll
        for (int r = 0; r < 8; ++r) {
            float e = embT[k][b0 + r];
            acc[r][0] += e * w0;
            acc[r][1] += e * w1;
        }
    }
#pragma unroll
    for (int r = 0; r < 8; ++r) {
        float* o = xz + ((size_t)t * B + (b0 + r)) * G4 + n;
        o[0] = acc[r][0];
        o[1] = acc[r][1];
    }
}

// ---------------------------------------------------------------------------
// Kernel 3: FUSED LSTM — all encoder+decoder timesteps in ONE launch.
// One workgroup per batch row (rows are independent in the recurrence).
// h kept in LDS (fp32), c in registers; weights streamed from L2 via the
// packed layout; 2-deep register ping-pong pipeline; 512 threads (8 waves).
// Thread tid owns gate columns {2*tid, 2*tid+1}; thread n<256 owns h[n],c[n].
// Encoder mask (freeze past len[b]) == early exit at len[b] (monotone mask).
// ---------------------------------------------------------------------------
__global__ __launch_bounds__(512) void lstm_fused(const float* __restrict__ WpkE,
                                                  const float* __restrict__ WpkD,
                                                  const float* __restrict__ xz,
                                                  const int* __restrict__ len,
                                                  ushort_t* __restrict__ hs) {
    int b   = blockIdx.x;
    int tid = threadIdx.x;
    __shared__ __attribute__((aligned(16))) float hsh[H];
    __shared__ __attribute__((aligned(16))) float zs[G4];

    if (tid < H) hsh[tid] = 0.f;
    float creg = 0.f;
    __syncthreads();

    int tlim = len[b];
    if (tlim > TX) tlim = TX;
    if (tlim < 0)  tlim = 0;
    int nsteps = tlim + TY;

#define LOADW(W0, W1, W2, W3, Hh0, Hh1, kb_)                                   \
    {                                                                          \
        const float4* wp = wbase + (size_t)(kb_) * 2048;                       \
        W0 = wp[0]; W1 = wp[1]; W2 = wp[2]; W3 = wp[3];                        \
        const float4* hp = (const float4*)&hsh[(kb_) * 8];                     \
        Hh0 = hp[0]; Hh1 = hp[1];                                              \
    }

#define FMA8(W0, W1, W2, W3, Hh0, Hh1)                                         \
    {                                                                          \
        accx += Hh0.x * W0.x; accy += Hh0.x * W0.y;                            \
        accx += Hh0.y * W0.z; accy += Hh0.y * W0.w;                            \
        accx += Hh0.z * W1.x; accy += Hh0.z * W1.y;                            \
        accx += Hh0.w * W1.z; accy += Hh0.w * W1.w;                            \
        accx += Hh1.x * W2.x; accy += Hh1.x * W2.y;                            \
        accx += Hh1.y * W2.z; accy += Hh1.y * W2.w;                            \
        accx += Hh1.z * W3.x; accy += Hh1.z * W3.y;                            \
        accx += Hh1.w * W3.z; accy += Hh1.w * W3.w;                            \
    }

    for (int t = 0; t < nsteps; ++t) {
        int is_dec = (t >= tlim) ? 1 : 0;
        int tx = is_dec ? (TX + t - tlim) : t;
        const float* Wpk = is_dec ? WpkD : WpkE;
        const float* xzt = xz + ((size_t)tx * B + b) * G4;

        float accx = xzt[2 * tid];
        float accy = xzt[2 * tid + 1];

        const float4* wbase = (const float4*)Wpk + (size_t)tid * 4;  // tid*16 floats
        float4 wA0, wA1, wA2, wA3, wB0, wB1, wB2, wB3;
        float4 hA0, hA1, hB0, hB1;

        LOADW(wA0, wA1, wA2, wA3, hA0, hA1, 0);
        for (int kb = 0; kb < 32; kb += 2) {
            LOADW(wB0, wB1, wB2, wB3, hB0, hB1, kb + 1);
            FMA8(wA0, wA1, wA2, wA3, hA0, hA1);
            if (kb + 2 < 32) LOADW(wA0, wA1, wA2, wA3, hA0, hA1, kb + 2);
            FMA8(wB0, wB1, wB2, wB3, hB0, hB1);
        }

        zs[2 * tid]     = accx;
        zs[2 * tid + 1] = accy;
        __syncthreads();

        if (tid < H) {
            float zi = zs[tid];
            float zj = zs[tid + H];
            float zf = zs[tid + 2 * H];
            float zo = zs[tid + 3 * H];
            float si = 1.f / (1.f + __expf(-zi));
            float sf = 1.f / (1.f + __expf(-(zf + 1.0f)));   // FORGET_BIAS = 1
            float so = 1.f / (1.f + __expf(-zo));
            float tj = tanhf(zj);
            creg = creg * sf + si * tj;
            float nh = tanhf(creg) * so;
            hsh[tid] = nh;
            if (is_dec) hs[((size_t)b * TY + (t - tlim)) * H + tid] = f2b(nh);
        }
        __syncthreads();
    }
#undef LOADW
#undef FMA8
}

// ---------------------------------------------------------------------------
// Kernel 4: projection GEMM  out[m][v] = sum_k hs[m][k] * WpT[v][k]
// M=2048, N=50000, K=256. 128x128 tiles, 4 waves, 16x16x32 bf16 MFMA.
// ---------------------------------------------------------------------------
typedef __attribute__((ext_vector_type(8))) short bf16x8;
typedef __attribute__((ext_vector_type(4))) float f32x4;

__global__ __launch_bounds__(256) void proj_gemm(const ushort_t* __restrict__ hs,
                                                 const ushort_t* __restrict__ WpT,
                                                 void* __restrict__ outv,
                                                 const int* __restrict__ flag) {
    int isf32 = *flag;
    int bx = blockIdx.x;  // 391 n-tiles
    int by = blockIdx.y;  // 16 m-tiles
    int m0 = by * 128, n0 = bx * 128;
    int tid = threadIdx.x;
    int w = tid >> 6, l = tid & 63;
    int qm = (w & 1) * 64, qn = (w >> 1) * 64;

    __shared__ __attribute__((aligned(16))) ushort_t As[128 * 32];
    __shared__ __attribute__((aligned(16))) ushort_t Bs[128 * 32];

    f32x4 acc[4][4] = {};
    int lr = l & 15, lg = l >> 4;

    for (int kk = 0; kk < 8; ++kk) {
        int k0 = kk * 32;
        __syncthreads();
        {
            int row = tid >> 2;
            int off = (tid & 3) * 8;   // ushort offset, 16B granular
            *(uint4*)&As[row * 32 + off] =
                *(const uint4*)&hs[((size_t)(m0 + row)) * H + k0 + off];
            *(uint4*)&As[(row + 64) * 32 + off] =
                *(const uint4*)&hs[((size_t)(m0 + row + 64)) * H + k0 + off];
            int nr0 = n0 + row;       if (nr0 > VCB - 1) nr0 = VCB - 1;
            int nr1 = n0 + row + 64;  if (nr1 > VCB - 1) nr1 = VCB - 1;
            *(uint4*)&Bs[row * 32 + off] =
                *(const uint4*)&WpT[(size_t)nr0 * H + k0 + off];
            *(uint4*)&Bs[(row + 64) * 32 + off] =
                *(const uint4*)&WpT[(size_t)nr1 * H + k0 + off];
        }
        __syncthreads();

        bf16x8 a[4], bf[4];
#pragma unroll
        for (int i = 0; i < 4; ++i)
            a[i] = *(const bf16x8*)&As[(qm + 16 * i + lr) * 32 + lg * 8];
#pragma unroll
        for (int j = 0; j < 4; ++j)
            bf[j] = *(const bf16x8*)&Bs[(qn + 16 * j + lr) * 32 + lg * 8];
#pragma unroll
        for (int i = 0; i < 4; ++i)
#pragma unroll
            for (int j = 0; j < 4; ++j)
                acc[i][j] = __builtin_amdgcn_mfma_f32_16x16x32_bf16(a[i], bf[j], acc[i][j], 0, 0, 0);
    }

    if (isf32) {
        float* out = (float*)outv;
#pragma unroll
        for (int i = 0; i < 4; ++i)
#pragma unroll
            for (int j = 0; j < 4; ++j) {
                int mrow = m0 + qm + 16 * i + lg * 4;
                int ncol = n0 + qn + 16 * j + lr;
                if (ncol < VCB) {
#pragma unroll
                    for (int r = 0; r < 4; ++r)
                        out[(size_t)(mrow + r) * VCB + ncol] = acc[i][j][r];
                }
            }
    } else {
        ushort_t* out = (ushort_t*)outv;
#pragma unroll
        for (int i = 0; i < 4; ++i)
#pragma unroll
            for (int j = 0; j < 4; ++j) {
                int mrow = m0 + qm + 16 * i + lg * 4;
                int ncol = n0 + qn + 16 * j + lr;
                if (ncol < VCB) {
#pragma unroll
                    for (int r = 0; r < 4; ++r)
                        out[(size_t)(mrow + r) * VCB + ncol] = f2b(acc[i][j][r]);
                }
            }
    }
}

// ---------------------------------------------------------------------------
extern "C" void kernel_launch(void* const* d_in, const int* in_sizes, int n_in,
                              void* d_out, int out_size, void* d_ws, size_t ws_size,
                              hipStream_t stream) {
    const int* enc_in = (const int*)d_in[0];
    const int* dec_in = (const int*)d_in[1];
    const int* lens   = (const int*)d_in[2];
    const void* E      = d_in[3];
    const void* W_enc  = d_in[4];
    const void* b_enc  = d_in[5];
    const void* W_dec  = d_in[6];
    const void* b_dec  = d_in[7];
    const void* W_proj = d_in[8];

    char* ws = (char*)d_ws;
    size_t o = 0;
    int*   flag = (int*)(ws + o);        o += 256;
    float* xz   = (float*)(ws + o);      o += (size_t)TT * B * G4 * 4;     // 25.17 MB
    ushort_t* WpT = (ushort_t*)(ws + o); o += (size_t)VCB * H * 2;         // 25.6 MB
    float* Wce  = (float*)(ws + o);      o += (size_t)(D + H) * G4 * 4;    // 1.57 MB
    float* Wcd  = (float*)(ws + o);      o += (size_t)(D + H) * G4 * 4;    // 1.57 MB
    float* bce  = (float*)(ws + o);      o += 4096;
    float* bcd  = (float*)(ws + o);      o += 4096;
    float* WpkE = (float*)(ws + o);      o += (size_t)H * G4 * 4;          // 1 MB
    float* WpkD = (float*)(ws + o);      o += (size_t)H * G4 * 4;          // 1 MB
    ushort_t* hs = (ushort_t*)(ws + o);  o += (size_t)B * TY * H * 2;      // 1 MB

    detect_dtype<<<1, 256, 0, stream>>>((const ushort_t*)E, flag);
    canon_w<<<1536, 256, 0, stream>>>(W_enc, b_enc, W_dec, b_dec,
                                      Wce, bce, Wcd, bcd, flag);
    pack_wh<<<dim3(1024, 2), 256, 0, stream>>>(Wce, Wcd, WpkE, WpkD);
    transpose_wp<<<dim3(782, 4), 256, 0, stream>>>(W_proj, WpT, flag);
    embed_xw<<<dim3(16, TT), 128, 0, stream>>>(enc_in, dec_in, E,
                                               Wce, bce, Wcd, bcd, xz, flag);

    lstm_fused<<<B, 512, 0, stream>>>(WpkE, WpkD, xz, lens, hs);

    proj_gemm<<<dim3(391, 16), 256, 0, stream>>>(hs, WpT, d_out, flag);
}

// Round 2
// 974.574 us; speedup vs baseline: 3.3681x; 3.3337x over previous
//
#include <hip/hip_runtime.h>
#include <hip/hip_bf16.h>
#include <stdint.h>

// Problem constants
#define B   32
#define TX  128
#define TY  64
#define VCB 50000
#define D   128
#define H   256
#define G4  1024   // 4*H
#define TT  192    // TX+TY

typedef unsigned short ushort_t;

__device__ __forceinline__ float b2f(ushort_t u) {
    union { unsigned int i; float f; } v;
    v.i = ((unsigned int)u) << 16;
    return v.f;
}

__device__ __forceinline__ ushort_t f2b(float f) {
    union { float f; unsigned int i; } v;
    v.f = f;
    unsigned int i = v.i;
    unsigned int r = (i + 0x7fffu + ((i >> 16) & 1u)) >> 16;  // RNE
    return (ushort_t)r;
}

__device__ __forceinline__ unsigned int f2u(float f) {
    union { float f; unsigned int i; } v; v.f = f; return v.i;
}
__device__ __forceinline__ float u2f(unsigned int u) {
    union { unsigned int i; float f; } v; v.i = u; return v.f;
}

// Flag-aware load: isf32 ? fp32 array : bf16 array. Branch is wave-uniform.
__device__ __forceinline__ float ldf(const void* p, size_t i, int isf32) {
    if (isf32) return ((const float*)p)[i];
    return b2f(((const ushort_t*)p)[i]);
}

// ---------------------------------------------------------------------------
// Kernel 0: dtype detection. Interpret E's first 4096 u16 as bf16; genuine
// bf16 data (normal*0.05) has max|v| ~0.25. fp32 data's low-half u16s have
// random exponent bits -> max|v| is astronomically large. flag=1 => fp32.
// ---------------------------------------------------------------------------
__global__ __launch_bounds__(256) void detect_dtype(const ushort_t* __restrict__ E16,
                                                    int* __restrict__ flag) {
    __shared__ float red[256];
    int tid = threadIdx.x;
    float m = 0.f;
#pragma unroll
    for (int j = 0; j < 16; ++j) {
        float v = fabsf(b2f(E16[tid * 16 + j]));
        if (v > m) m = v;
    }
    red[tid] = m;
    __syncthreads();
    for (int s = 128; s > 0; s >>= 1) {
        if (tid < s && red[tid + s] > red[tid]) red[tid] = red[tid + s];
        __syncthreads();
    }
    if (tid == 0) flag[0] = (red[0] > 1.0f) ? 1 : 0;
}

// ---------------------------------------------------------------------------
// Kernel 0b: canonicalize LSTM weights/biases to fp32 (exact either way).
// ---------------------------------------------------------------------------
__global__ __launch_bounds__(256) void canon_w(const void* __restrict__ We,
                                               const void* __restrict__ be,
                                               const void* __restrict__ Wd,
                                               const void* __restrict__ bd,
                                               float* __restrict__ Wce,
                                               float* __restrict__ bce,
                                               float* __restrict__ Wcd,
                                               float* __restrict__ bcd,
                                               const int* __restrict__ flag) {
    int isf32 = *flag;
    int i = blockIdx.x * 256 + threadIdx.x;
    const int NW = (D + H) * G4;   // 393216
    if (i < NW) {
        Wce[i] = ldf(We, i, isf32);
        Wcd[i] = ldf(Wd, i, isf32);
    }
    if (i < G4) {
        bce[i] = ldf(be, i, isf32);
        bcd[i] = ldf(bd, i, isf32);
    }
}

// ---------------------------------------------------------------------------
// Kernel 1: transpose W_proj (H x V) -> WpT (V x H) bf16, k-contiguous rows.
// ---------------------------------------------------------------------------
__global__ __launch_bounds__(256) void transpose_wp(const void* __restrict__ Wp,
                                                    ushort_t* __restrict__ WpT,
                                                    const int* __restrict__ flag) {
    int isf32 = *flag;
    int v0 = blockIdx.x * 64;
    int k0 = blockIdx.y * 64;
    __shared__ ushort_t tile[64][65];
    int tid = threadIdx.x;
    int vl = tid & 63, p0 = tid >> 6;     // p0 in [0,4)
    for (int p = 0; p < 16; ++p) {
        int k = k0 + p0 + p * 4;          // k < 256 always
        int v = v0 + vl;
        float x = (v < VCB) ? ldf(Wp, (size_t)k * VCB + v, isf32) : 0.f;
        tile[p0 + p * 4][vl] = f2b(x);
    }
    __syncthreads();
    int kl = tid & 63, q0 = tid >> 6;
    for (int p = 0; p < 16; ++p) {
        int v = v0 + q0 + p * 4;
        if (v < VCB) WpT[(size_t)v * H + (k0 + kl)] = tile[kl][q0 + p * 4];
    }
}

// ---------------------------------------------------------------------------
// Kernel 2: embedding gather + x-part of gate GEMM for all 192 steps (fp32).
// xz[t][b][g] = sum_k emb(t,b,k) * Wx[k][g] + bias[g]
// ---------------------------------------------------------------------------
__global__ __launch_bounds__(128) void embed_xw(const int* __restrict__ enc_in,
                                                const int* __restrict__ dec_in,
                                                const void* __restrict__ E,
                                                const float* __restrict__ Wce,
                                                const float* __restrict__ bce,
                                                const float* __restrict__ Wcd,
                                                const float* __restrict__ bcd,
                                                float* __restrict__ xz,
                                                const int* __restrict__ flag) {
    int isf32 = *flag;
    int t  = blockIdx.y;          // 0..191
    int n0 = blockIdx.x * 64;     // 16 n-slices
    int tid = threadIdx.x;        // 0..127 (= k index)
    __shared__ float embT[D][33]; // [k][b], padded
    __shared__ int tok[B];

    const float* Wc   = (t < TX) ? Wce : Wcd;
    const float* bias = (t < TX) ? bce : bcd;

    if (tid < B)
        tok[tid] = (t < TX) ? enc_in[tid * TX + t] : dec_in[tid * TY + (t - TX)];
    __syncthreads();

    for (int p = 0; p < B; ++p)
        embT[tid][p] = ldf(E, (size_t)tok[p] * D + tid, isf32);
    __syncthreads();

    int nl = tid & 31;            // n-pair index
    int bg = tid >> 5;            // 0..3
    int n  = n0 + nl * 2;
    int b0 = bg * 8;
    float acc[8][2];
    float bi0 = bias[n], bi1 = bias[n + 1];
#pragma unroll
    for (int r = 0; r < 8; ++r) { acc[r][0] = bi0; acc[r][1] = bi1; }

    for (int k = 0; k < D; ++k) {
        const float* wr = Wc + (size_t)k * G4 + n;
        float w0 = wr[0], w1 = wr[1];
#pragma unroll
        for (int r = 0; r < 8; ++r) {
            float e = embT[k][b0 + r];
            acc[r][0] += e * w0;
            acc[r][1] += e * w1;
        }
    }
#pragma unroll
    for (int r = 0; r < 8; ++r) {
        float* o = xz + ((size_t)t * B + (b0 + r)) * G4 + n;
        o[0] = acc[r][0];
        o[1] = acc[r][1];
    }
}

// ---------------------------------------------------------------------------
// Kernel 3: PERSISTENT FUSED LSTM — weights live in REGISTERS for the whole
// sequence; zero per-step weight traffic.
//
// Grid: 256 blocks = 32 rows x 8 column-groups; 1 block/CU (cooperative
// launch guarantees co-residency). Block (r,g) owns h-units
// n = g*32 .. g*32+31 (their 4 gate columns each = 128 columns).
// Thread (c = tid&127, s = tid>>7): column-local c, k-quarter s; holds
// 64 enc + 64 dec weights in VGPRs (128 regs). Per step:
//   1. partial z over its k-quarter (h broadcast from LDS), split-k reduce
//      via LDS (zp[4][128]),
//   2. tid<32 gate math (c register-resident), publish h via 8-byte
//      agent-scope atomic carrying (tag = t+1, value = h bits); parity
//      double-buffer makes overwrite-before-read impossible (a writer can
//      only reach tag t+3 on a slot after every reader consumed tag t+1),
//   3. tid<256 poll their unit's slot until tag matches, refill LDS h.
// Encoder freeze past len[r] == early transition to decoder (mask monotone).
// ---------------------------------------------------------------------------
__global__ __launch_bounds__(512, 2) void lstm_fused(const float* __restrict__ Wce,
                                                     const float* __restrict__ Wcd,
                                                     const float* __restrict__ xz,
                                                     const int* __restrict__ len,
                                                     ushort_t* __restrict__ hs,
                                                     unsigned long long* __restrict__ hg) {
    int bid = blockIdx.x;
    int r = bid >> 3;       // batch row
    int g = bid & 7;        // column group
    int tid = threadIdx.x;
    int c   = tid & 127;    // local column 0..127
    int s   = tid >> 7;     // k-quarter 0..3
    int q   = c >> 5;       // gate 0..3 (i,j,f,o)
    int nl  = c & 31;       // unit within group
    int gcol = q * 256 + g * 32 + nl;  // global gate column
    int k0  = s * 64;

    __shared__ __attribute__((aligned(16))) float hsh[H];
    __shared__ float zp[4][128];

    // ---- one-time: load this thread's weights (enc + dec) into registers
    float4 we[16], wd[16];
#pragma unroll
    for (int j = 0; j < 16; ++j) {
        const float* pe = Wce + (size_t)(D + k0 + 4 * j) * G4 + gcol;
        we[j] = make_float4(pe[0], pe[G4], pe[2 * G4], pe[3 * G4]);
        const float* pd = Wcd + (size_t)(D + k0 + 4 * j) * G4 + gcol;
        wd[j] = make_float4(pd[0], pd[G4], pd[2 * G4], pd[3 * G4]);
    }

    if (tid < H) hsh[tid] = 0.f;
    float creg = 0.f;   // cell state for unit (g*32 + tid), tid < 32
    __syncthreads();

    int tlim = len[r];
    if (tlim > TX) tlim = TX;
    if (tlim < 0)  tlim = 0;
    int nsteps = tlim + TY;

    for (int t = 0; t < nsteps; ++t) {
        int is_dec = (t >= tlim) ? 1 : 0;
        int tx = is_dec ? (TX + t - tlim) : t;

        // prefetch xz (x-part + bias) for the gate threads; hidden under GEMM
        float xzi = 0.f, xzj = 0.f, xzf = 0.f, xzo = 0.f;
        if (tid < 32) {
            const float* xzt = xz + ((size_t)tx * B + r) * G4 + g * 32 + nl;
            xzi = xzt[0];
            xzj = xzt[256];
            xzf = xzt[512];
            xzo = xzt[768];
        }

        // ---- GEMM partial: this thread's column x its k-quarter
        const float4* h4 = (const float4*)hsh + s * 16;
        float acc = 0.f;
        if (!is_dec) {
#pragma unroll
            for (int j = 0; j < 16; ++j) {
                float4 h = h4[j];
                acc += we[j].x * h.x + we[j].y * h.y + we[j].z * h.z + we[j].w * h.w;
            }
        } else {
#pragma unroll
            for (int j = 0; j < 16; ++j) {
                float4 h = h4[j];
                acc += wd[j].x * h.x + wd[j].y * h.y + wd[j].z * h.z + wd[j].w * h.w;
            }
        }
        zp[s][c] = acc;
        __syncthreads();

        // ---- gate math + publish (32 threads)
        if (tid < 32) {
            float zi = xzi + zp[0][nl]      + zp[1][nl]      + zp[2][nl]      + zp[3][nl];
            float zj = xzj + zp[0][32 + nl] + zp[1][32 + nl] + zp[2][32 + nl] + zp[3][32 + nl];
            float zf = xzf + zp[0][64 + nl] + zp[1][64 + nl] + zp[2][64 + nl] + zp[3][64 + nl];
            float zo = xzo + zp[0][96 + nl] + zp[1][96 + nl] + zp[2][96 + nl] + zp[3][96 + nl];
            float si = 1.f / (1.f + __expf(-zi));
            float sf = 1.f / (1.f + __expf(-(zf + 1.0f)));   // FORGET_BIAS = 1
            float so = 1.f / (1.f + __expf(-zo));
            float tj = tanhf(zj);
            creg = creg * sf + si * tj;
            float nh = tanhf(creg) * so;
            if (is_dec) hs[((size_t)r * TY + (t - tlim)) * H + (g * 32 + nl)] = f2b(nh);

            unsigned long long v =
                ((unsigned long long)(unsigned int)(t + 1) << 32) | (unsigned long long)f2u(nh);
            int slot = (t + 1) & 1;
            __hip_atomic_store(&hg[((size_t)slot * B + r) * H + g * 32 + nl], v,
                               __ATOMIC_RELAXED, __HIP_MEMORY_SCOPE_AGENT);
        }

        // ---- collect full h for next step (256 threads poll tagged values)
        if (t + 1 < nsteps) {
            if (tid < H) {
                unsigned int want = (unsigned int)(t + 1);
                int slot = (t + 1) & 1;
                unsigned long long* p = &hg[((size_t)slot * B + r) * H + tid];
                unsigned long long v;
                do {
                    v = __hip_atomic_load(p, __ATOMIC_RELAXED, __HIP_MEMORY_SCOPE_AGENT);
                } while ((unsigned int)(v >> 32) != want);
                hsh[tid] = u2f((unsigned int)v);
            }
            __syncthreads();
        }
    }
}

// ---------------------------------------------------------------------------
// Kernel 4: projection GEMM  out[m][v] = sum_k hs[m][k] * WpT[v][k]
// M=2048, N=50000, K=256. 128x128 tiles, 4 waves, 16x16x32 bf16 MFMA.
// ---------------------------------------------------------------------------
typedef __attribute__((ext_vector_type(8))) short bf16x8;
typedef __attribute__((ext_vector_type(4))) float f32x4;

__global__ __launch_bounds__(256) void proj_gemm(const ushort_t* __restrict__ hs,
                                                 const ushort_t* __restrict__ WpT,
                                                 void* __restrict__ outv,
                                                 const int* __restrict__ flag) {
    int isf32 = *flag;
    int bx = blockIdx.x;  // 391 n-tiles
    int by = blockIdx.y;  // 16 m-tiles
    int m0 = by * 128, n0 = bx * 128;
    int tid = threadIdx.x;
    int w = tid >> 6, l = tid & 63;
    int qm = (w & 1) * 64, qn = (w >> 1) * 64;

    __shared__ __attribute__((aligned(16))) ushort_t As[128 * 32];
    __shared__ __attribute__((aligned(16))) ushort_t Bs[128 * 32];

    f32x4 acc[4][4] = {};
    int lr = l & 15, lg = l >> 4;

    for (int kk = 0; kk < 8; ++kk) {
        int k0 = kk * 32;
        __syncthreads();
        {
            int row = tid >> 2;
            int off = (tid & 3) * 8;   // ushort offset, 16B granular
            *(uint4*)&As[row * 32 + off] =
                *(const uint4*)&hs[((size_t)(m0 + row)) * H + k0 + off];
            *(uint4*)&As[(row + 64) * 32 + off] =
                *(const uint4*)&hs[((size_t)(m0 + row + 64)) * H + k0 + off];
            int nr0 = n0 + row;       if (nr0 > VCB - 1) nr0 = VCB - 1;
            int nr1 = n0 + row + 64;  if (nr1 > VCB - 1) nr1 = VCB - 1;
            *(uint4*)&Bs[row * 32 + off] =
                *(const uint4*)&WpT[(size_t)nr0 * H + k0 + off];
            *(uint4*)&Bs[(row + 64) * 32 + off] =
                *(const uint4*)&WpT[(size_t)nr1 * H + k0 + off];
        }
        __syncthreads();

        bf16x8 a[4], bf[4];
#pragma unroll
        for (int i = 0; i < 4; ++i)
            a[i] = *(const bf16x8*)&As[(qm + 16 * i + lr) * 32 + lg * 8];
#pragma unroll
        for (int j = 0; j < 4; ++j)
            bf[j] = *(const bf16x8*)&Bs[(qn + 16 * j + lr) * 32 + lg * 8];
#pragma unroll
        for (int i = 0; i < 4; ++i)
#pragma unroll
            for (int j = 0; j < 4; ++j)
                acc[i][j] = __builtin_amdgcn_mfma_f32_16x16x32_bf16(a[i], bf[j], acc[i][j], 0, 0, 0);
    }

    if (isf32) {
        float* out = (float*)outv;
#pragma unroll
        for (int i = 0; i < 4; ++i)
#pragma unroll
            for (int j = 0; j < 4; ++j) {
                int mrow = m0 + qm + 16 * i + lg * 4;
                int ncol = n0 + qn + 16 * j + lr;
                if (ncol < VCB) {
#pragma unroll
                    for (int r = 0; r < 4; ++r)
                        out[(size_t)(mrow + r) * VCB + ncol] = acc[i][j][r];
                }
            }
    } else {
        ushort_t* out = (ushort_t*)outv;
#pragma unroll
        for (int i = 0; i < 4; ++i)
#pragma unroll
            for (int j = 0; j < 4; ++j) {
                int mrow = m0 + qm + 16 * i + lg * 4;
                int ncol = n0 + qn + 16 * j + lr;
                if (ncol < VCB) {
#pragma unroll
                    for (int r = 0; r < 4; ++r)
                        out[(size_t)(mrow + r) * VCB + ncol] = f2b(acc[i][j][r]);
                }
            }
    }
}

// ---------------------------------------------------------------------------
extern "C" void kernel_launch(void* const* d_in, const int* in_sizes, int n_in,
                              void* d_out, int out_size, void* d_ws, size_t ws_size,
                              hipStream_t stream) {
    const int* enc_in = (const int*)d_in[0];
    const int* dec_in = (const int*)d_in[1];
    const int* lens   = (const int*)d_in[2];
    const void* E      = d_in[3];
    const void* W_enc  = d_in[4];
    const void* b_enc  = d_in[5];
    const void* W_dec  = d_in[6];
    const void* b_dec  = d_in[7];
    const void* W_proj = d_in[8];

    char* ws = (char*)d_ws;
    size_t o = 0;
    int*   flag = (int*)(ws + o);        o += 256;
    float* xz   = (float*)(ws + o);      o += (size_t)TT * B * G4 * 4;     // 25.17 MB
    ushort_t* WpT = (ushort_t*)(ws + o); o += (size_t)VCB * H * 2;         // 25.6 MB
    float* Wce  = (float*)(ws + o);      o += (size_t)(D + H) * G4 * 4;    // 1.57 MB
    float* Wcd  = (float*)(ws + o);      o += (size_t)(D + H) * G4 * 4;    // 1.57 MB
    float* bce  = (float*)(ws + o);      o += 4096;
    float* bcd  = (float*)(ws + o);      o += 4096;
    unsigned long long* hg = (unsigned long long*)(ws + o);
                                         o += (size_t)2 * B * H * 8;       // 128 KB
    ushort_t* hs = (ushort_t*)(ws + o);  o += (size_t)B * TY * H * 2;      // 1 MB

    detect_dtype<<<1, 256, 0, stream>>>((const ushort_t*)E, flag);
    canon_w<<<1536, 256, 0, stream>>>(W_enc, b_enc, W_dec, b_dec,
                                      Wce, bce, Wcd, bcd, flag);
    transpose_wp<<<dim3(782, 4), 256, 0, stream>>>(W_proj, WpT, flag);
    embed_xw<<<dim3(16, TT), 128, 0, stream>>>(enc_in, dec_in, E,
                                               Wce, bce, Wcd, bcd, xz, flag);

    // zero the tag buffer (tags start at 1; 0 == "not yet written")
    hipMemsetAsync(hg, 0, (size_t)2 * B * H * 8, stream);

    // persistent cooperative LSTM: 256 blocks, 1 per CU
    {
        const float* WceP = Wce;
        const float* WcdP = Wcd;
        const float* xzP  = xz;
        const int*   lenP = lens;
        ushort_t*    hsP  = hs;
        unsigned long long* hgP = hg;
        void* args[] = { (void*)&WceP, (void*)&WcdP, (void*)&xzP,
                         (void*)&lenP, (void*)&hsP, (void*)&hgP };
        hipLaunchCooperativeKernel((const void*)lstm_fused, dim3(256), dim3(512),
                                   args, 0, stream);
    }

    proj_gemm<<<dim3(391, 16), 256, 0, stream>>>(hs, WpT, d_out, flag);
}